// Round 2
// baseline (465.265 us; speedup 1.0000x reference)
//
#include <hip/hip_runtime.h>

typedef _Float16 f16;
typedef _Float16 f16x8 __attribute__((ext_vector_type(8)));
typedef float f32x4 __attribute__((ext_vector_type(4)));

#define SEQ   196
#define EMB   768
#define NHEAD 12
#define HD    64
#define BATCH 256
#define TOK   (BATCH*SEQ)      /* 50176 */
#define QKVN  (3*EMB)          /* 2304  */
#define CLSK  (SEQ*EMB)        /* 150528 */

// ---------------- f32 -> f16 convert, 8 elems/thread ----------------
__global__ __launch_bounds__(256) void k_cvt8(const float* __restrict__ in,
                                              f16* __restrict__ out, int n8) {
  int i = blockIdx.x * 256 + threadIdx.x;
  if (i >= n8) return;
  const float4* p = (const float4*)in + (size_t)i * 2;
  float4 a = p[0], b = p[1];
  f16x8 o;
  o[0]=(f16)a.x; o[1]=(f16)a.y; o[2]=(f16)a.z; o[3]=(f16)a.w;
  o[4]=(f16)b.x; o[5]=(f16)b.y; o[6]=(f16)b.z; o[7]=(f16)b.w;
  *((f16x8*)out + i) = o;
}

// ------------- W[K][N] f32 -> WT[N][K] f16 (tiled transpose) -------------
__global__ __launch_bounds__(256) void k_transpose_cvt(const float* __restrict__ W,
                                                       f16* __restrict__ WT,
                                                       int K, int N) {
  __shared__ float tile[32][33];
  int n0 = blockIdx.x * 32, k0 = blockIdx.y * 32;
  int t = threadIdx.x, tx = t & 31, ty = t >> 5;
  #pragma unroll
  for (int i = 0; i < 4; ++i) {
    int r = ty + i * 8;
    tile[r][tx] = W[(size_t)(k0 + r) * N + n0 + tx];
  }
  __syncthreads();
  #pragma unroll
  for (int i = 0; i < 4; ++i) {
    int r = ty + i * 8;
    WT[(size_t)(n0 + r) * K + k0 + tx] = (f16)tile[tx][r];
  }
}

// ---------------- GEMM: C[M][N] = A[M][K] * B^T[N][K] + bias, f16 in, f16 out
// 128x128 tile, BK=64, 4 waves (2x2), 64x64 per wave, mfma_f32_16x16x32_f16.
// LDS chunks (16B) XOR-swizzled: chunk c of row r holds global chunk c^(r&7);
// applied on the global SOURCE address (global_load_lds writes linearly) and
// inverted on the ds_read side -> conflict-free ds_read_b128.
__global__ __launch_bounds__(256) void k_gemm_bias(
    const f16* __restrict__ A, const f16* __restrict__ Bm,
    const float* __restrict__ bias, f16* __restrict__ C,
    int M, int N, int K) {
  __shared__ f16 As[128 * 64];
  __shared__ f16 Bs[128 * 64];
  const int t = threadIdx.x;
  const int l = t & 63;
  const int w = t >> 6;
  const int wr = w >> 1, wc = w & 1;
  const int bm = blockIdx.y, bn = blockIdx.x;
  const size_t rowA0 = (size_t)bm * 128, rowB0 = (size_t)bn * 128;

  f32x4 acc[4][4] = {};

  for (int k0 = 0; k0 < K; k0 += 64) {
    if (k0) __syncthreads();
    // stage A,B tiles: 1024 16B chunks each, 4 per thread
    #pragma unroll
    for (int i = 0; i < 4; ++i) {
      int q = i * 256 + t;
      int r = q >> 3, c = q & 7;
      int cs = c ^ (r & 7);                      // pre-swizzled source chunk
      const f16* ga = A  + (rowA0 + r) * K + k0 + cs * 8;
      const f16* gb = Bm + (rowB0 + r) * K + k0 + cs * 8;
      f16* la = As + (size_t)(i * 256 + w * 64) * 8;  // wave-uniform base
      f16* lb = Bs + (size_t)(i * 256 + w * 64) * 8;
      __builtin_amdgcn_global_load_lds((const __attribute__((address_space(1))) void*)ga,
                                       (__attribute__((address_space(3))) void*)la, 16, 0, 0);
      __builtin_amdgcn_global_load_lds((const __attribute__((address_space(1))) void*)gb,
                                       (__attribute__((address_space(3))) void*)lb, 16, 0, 0);
    }
    __syncthreads();
    #pragma unroll
    for (int ks = 0; ks < 2; ++ks) {
      f16x8 av[4], bv[4];
      const int k8 = ks * 4 + (l >> 4);
      #pragma unroll
      for (int m = 0; m < 4; ++m) {
        int r = wr * 64 + m * 16 + (l & 15);
        av[m] = *(const f16x8*)((const char*)As + r * 128 + ((k8 ^ (r & 7)) << 4));
      }
      #pragma unroll
      for (int n = 0; n < 4; ++n) {
        int r = wc * 64 + n * 16 + (l & 15);
        bv[n] = *(const f16x8*)((const char*)Bs + r * 128 + ((k8 ^ (r & 7)) << 4));
      }
      #pragma unroll
      for (int m = 0; m < 4; ++m)
        #pragma unroll
        for (int n = 0; n < 4; ++n)
          acc[m][n] = __builtin_amdgcn_mfma_f32_16x16x32_f16(av[m], bv[n], acc[m][n], 0, 0, 0);
    }
  }
  // epilogue: C/D layout col = l&15, row = (l>>4)*4 + j  (guide m89/m91)
  #pragma unroll
  for (int n = 0; n < 4; ++n) {
    int gcol = bn * 128 + wc * 64 + n * 16 + (l & 15);
    float bs = bias[gcol];
    #pragma unroll
    for (int m = 0; m < 4; ++m) {
      int grow0 = bm * 128 + wr * 64 + m * 16 + (l >> 4) * 4;
      #pragma unroll
      for (int j = 0; j < 4; ++j)
        C[(size_t)(grow0 + j) * N + gcol] = (f16)(acc[m][n][j] + bs);
    }
  }
}

// ---------------- per-token 12x12 attention over heads ----------------
// qkv row layout: head h -> [h*192 .. h*192+63]=q, +64..127=k, +128..191=v
__global__ __launch_bounds__(64) void k_attn(const f16* __restrict__ qkv,
                                             f16* __restrict__ aout) {
  const int tok = blockIdx.x;
  const int l = threadIdx.x;
  __shared__ f16 row[QKVN];
  __shared__ float sc[144];
  __shared__ float aw[144];
  const uint2* src = (const uint2*)(qkv + (size_t)tok * QKVN);
  uint2* dst = (uint2*)row;
  #pragma unroll
  for (int i = 0; i < 9; ++i) dst[l + i * 64] = src[l + i * 64];
  __syncthreads();
  for (int p = l; p < 144; p += 64) {
    int i = p / 12, j = p - i * 12;
    const f16x8* q8 = (const f16x8*)(row + i * 192);
    const f16x8* k8 = (const f16x8*)(row + j * 192 + 64);
    float s = 0.f;
    #pragma unroll
    for (int d8 = 0; d8 < 8; ++d8) {
      f16x8 a = q8[d8], b = k8[d8];
      #pragma unroll
      for (int e = 0; e < 8; ++e) s += (float)a[e] * (float)b[e];
    }
    sc[p] = s * 0.125f;
  }
  __syncthreads();
  if (l < 12) {
    float m = -1e30f;
    #pragma unroll
    for (int j = 0; j < 12; ++j) m = fmaxf(m, sc[l * 12 + j]);
    float e[12], sum = 0.f;
    #pragma unroll
    for (int j = 0; j < 12; ++j) { e[j] = __expf(sc[l * 12 + j] - m); sum += e[j]; }
    float inv = 1.f / sum;
    #pragma unroll
    for (int j = 0; j < 12; ++j) aw[l * 12 + j] = e[j] * inv;
  }
  __syncthreads();
  float vv[12];
  #pragma unroll
  for (int j = 0; j < 12; ++j) vv[j] = (float)row[j * 192 + 128 + l];
  f16* op = aout + (size_t)tok * EMB;
  #pragma unroll
  for (int i = 0; i < 12; ++i) {
    float o = 0.f;
    #pragma unroll
    for (int j = 0; j < 12; ++j) o += aw[i * 12 + j] * vv[j];
    op[i * 64 + l] = (f16)o;
  }
}

// ---------------- classifier: per-batch 150528-dim dot with 3 cols ----------------
__global__ __launch_bounds__(256) void k_cls(const f16* __restrict__ out2,
                                             const float* __restrict__ cls_w,
                                             const float* __restrict__ cls_b,
                                             float* __restrict__ logits) {
  const int b = blockIdx.x, t = threadIdx.x;
  const f16* r = out2 + (size_t)b * CLSK;
  float s0 = 0.f, s1 = 0.f, s2 = 0.f;
  for (int c8 = t; c8 < CLSK / 8; c8 += 256) {
    f16x8 v = *((const f16x8*)r + c8);
    float wv[24];
    const float4* wp = (const float4*)(cls_w + (size_t)c8 * 24);
    #pragma unroll
    for (int i = 0; i < 6; ++i) *(float4*)&wv[i * 4] = wp[i];
    #pragma unroll
    for (int e = 0; e < 8; ++e) {
      float f = (float)v[e];
      s0 += f * wv[e * 3 + 0];
      s1 += f * wv[e * 3 + 1];
      s2 += f * wv[e * 3 + 2];
    }
  }
  __shared__ float r0[256], r1[256], r2[256];
  r0[t] = s0; r1[t] = s1; r2[t] = s2;
  __syncthreads();
  for (int off = 128; off > 0; off >>= 1) {
    if (t < off) { r0[t] += r0[t + off]; r1[t] += r1[t + off]; r2[t] += r2[t + off]; }
    __syncthreads();
  }
  if (t == 0) {
    logits[b * 3 + 0] = r0[0] + cls_b[0];
    logits[b * 3 + 1] = r1[0] + cls_b[1];
    logits[b * 3 + 2] = r2[0] + cls_b[2];
  }
}

extern "C" void kernel_launch(void* const* d_in, const int* in_sizes, int n_in,
                              void* d_out, int out_size, void* d_ws, size_t ws_size,
                              hipStream_t stream) {
  (void)in_sizes; (void)n_in; (void)out_size;
  const float* x      = (const float*)d_in[0];
  const float* qkv_w  = (const float*)d_in[1];
  const float* qkv_b  = (const float*)d_in[2];
  const float* out_w  = (const float*)d_in[3];
  const float* out_b  = (const float*)d_in[4];
  const float* cls_w  = (const float*)d_in[5];
  const float* cls_b  = (const float*)d_in[6];
  float* logits = (float*)d_out;

  // workspace layout (bytes):
  //   [0, 77070336)                     x16      -> later reused as attn_out
  //   [77070336, 308281344)             qkv      -> later reused as out2
  //   [308281344, 311820288)            qkvT (2304x768 f16)
  //   [311820288, 312999936)            outT (768x768 f16)
  const size_t SZ_X16 = (size_t)TOK * EMB * 2;      // 77,070,336
  const size_t SZ_QKV = (size_t)TOK * QKVN * 2;     // 231,211,008
  const size_t SZ_QT  = (size_t)QKVN * EMB * 2;     // 3,538,944
  const size_t SZ_OT  = (size_t)EMB * EMB * 2;      // 1,179,648
  if (ws_size < SZ_X16 + SZ_QKV + SZ_QT + SZ_OT) return;  // insufficient scratch

  char* ws = (char*)d_ws;
  f16* x16  = (f16*)ws;
  f16* qkvb = (f16*)(ws + SZ_X16);
  f16* qkvT = (f16*)(ws + SZ_X16 + SZ_QKV);
  f16* outT = (f16*)(ws + SZ_X16 + SZ_QKV + SZ_QT);
  f16* attno = x16;   // overlay: x16 dead after GEMM1
  f16* out2  = qkvb;  // overlay: qkv dead after attention

  k_cvt8<<<dim3(TOK * EMB / 8 / 256), dim3(256), 0, stream>>>(x, x16, TOK * EMB / 8);
  k_transpose_cvt<<<dim3(QKVN / 32, EMB / 32), dim3(256), 0, stream>>>(qkv_w, qkvT, EMB, QKVN);
  k_transpose_cvt<<<dim3(EMB / 32, EMB / 32), dim3(256), 0, stream>>>(out_w, outT, EMB, EMB);
  k_gemm_bias<<<dim3(QKVN / 128, TOK / 128), dim3(256), 0, stream>>>(x16, qkvT, qkv_b, qkvb, TOK, QKVN, EMB);
  k_attn<<<dim3(TOK), dim3(64), 0, stream>>>(qkvb, attno);
  k_gemm_bias<<<dim3(EMB / 128, TOK / 128), dim3(256), 0, stream>>>(attno, outT, out_b, out2, TOK, EMB, EMB);
  k_cls<<<dim3(BATCH), dim3(256), 0, stream>>>(out2, cls_w, cls_b, logits);
}